// Round 14
// baseline (408.562 us; speedup 1.0000x reference)
//
#include <hip/hip_runtime.h>

#define NEG_SLOPE 0.2f

typedef __attribute__((ext_vector_type(8))) short bf16x8;
typedef __attribute__((ext_vector_type(4))) float f32x4;

__device__ inline unsigned short f2bf(float x) {
  unsigned int u = __float_as_uint(x);
  u += 0x7fffu + ((u >> 16) & 1u);
  return (unsigned short)(u >> 16);
}

// monotone float<->uint key for atomicMax on signed floats
__device__ inline unsigned fkey(float x) {
  unsigned u = __float_as_uint(x);
  return (u >> 31) ? ~u : (u | 0x80000000u);
}
__device__ inline float fkey_dec(unsigned k) {
  unsigned u = (k & 0x80000000u) ? (k ^ 0x80000000u) : ~k;
  return __uint_as_float(u);
}

// ---------------- CSR build ----------------

__global__ void hist_kernel(const int* __restrict__ ei, int* __restrict__ counts,
                            int E, int Etot) {
  int e = blockIdx.x * blockDim.x + threadIdx.x;
  if (e >= Etot) return;
  int d = (e < E) ? ei[E + e] : (e - E);   // self loop dst = e - E
  atomicAdd(&counts[d], 1);
}

// per-block partial sums, ZERO contended atomics
__global__ void mean_kernel(const float* __restrict__ ea, float* __restrict__ part, int E) {
  int i = blockIdx.x * blockDim.x + threadIdx.x;
  float s = 0.f;
  for (; i < E; i += gridDim.x * blockDim.x) s += ea[i];
#pragma unroll
  for (int off = 1; off < 64; off <<= 1) s += __shfl_xor(s, off, 64);
  __shared__ float ws_[4];
  if ((threadIdx.x & 63) == 0) ws_[threadIdx.x >> 6] = s;
  __syncthreads();
  if (threadIdx.x == 0) part[blockIdx.x] = ws_[0] + ws_[1] + ws_[2] + ws_[3];
}

// single-block full exclusive scan of counts[Nn] -> rowptr+cursor (+rowptr[Nn]),
// and meanv finalize from mean partials. Replaces 3 dispatches.
__global__ __launch_bounds__(1024) void scan_all(const int* __restrict__ counts,
                                                 int* __restrict__ rowptr,
                                                 int* __restrict__ cursor,
                                                 const float* __restrict__ meanpart,
                                                 float* __restrict__ meanv,
                                                 int Nn, int E, int npart) {
  __shared__ int wsum[16];
  __shared__ float fsum[16];
  int t = threadIdx.x, lane = t & 63, wv = t >> 6;
  // mean partials (npart<=1024)
  float f = (t < npart) ? meanpart[t] : 0.f;
#pragma unroll
  for (int off = 1; off < 64; off <<= 1) f += __shfl_xor(f, off, 64);
  if (lane == 0) fsum[wv] = f;
  // local sum of this thread's chunk
  const int CH = (Nn + 1023) >> 10;
  int base = t * CH;
  int lim = base + CH < Nn ? base + CH : Nn;
  int s = 0;
  for (int i = base; i < lim; i++) s += counts[i];
  // 64-lane inclusive scan
  int incl = s;
#pragma unroll
  for (int off = 1; off < 64; off <<= 1) {
    int y = __shfl_up(incl, off, 64);
    if (lane >= off) incl += y;
  }
  if (lane == 63) wsum[wv] = incl;
  __syncthreads();
  if (t == 0) {
    int acc = 0;
    for (int i = 0; i < 16; i++) { int x = wsum[i]; wsum[i] = acc; acc += x; }
    rowptr[Nn] = acc;
    float fa = 0.f;
    for (int i = 0; i < 16; i++) fa += fsum[i];
    *meanv = fa / (float)E;
  }
  __syncthreads();
  int run = wsum[wv] + incl - s;
  for (int i = base; i < lim; i++) {
    int c = counts[i];
    rowptr[i] = run;
    cursor[i] = run;
    run += c;
  }
}

// scatter resolves all indirection: epack[pos] = {src, edge_attr_value}
__global__ void scatter_kernel(const int* __restrict__ ei, const float* __restrict__ eattr,
                               const float* __restrict__ meanv,
                               int* __restrict__ cursor, int2* __restrict__ epack,
                               int E, int Etot) {
  int e = blockIdx.x * blockDim.x + threadIdx.x;
  if (e >= Etot) return;
  int d, s; float ea;
  if (e < E) { d = ei[E + e]; s = ei[e]; ea = eattr[e]; }
  else       { d = e - E;     s = e - E; ea = meanv[0]; }
  int pos = atomicAdd(&cursor[d], 1);
  epack[pos] = make_int2(s, __float_as_int(ea));
}

// W transposes + (block 384) we_att dots, one launch.
__global__ void wtrans_kernel(const float* __restrict__ W1, unsigned short* __restrict__ Wt1,
                              const float* __restrict__ W2, unsigned short* __restrict__ Wt2,
                              const float* __restrict__ We1, const float* __restrict__ atte1,
                              const float* __restrict__ We2, const float* __restrict__ atte2,
                              float* __restrict__ weatt1, float* __restrict__ weatt2) {
  int b = blockIdx.x;
  if (b >= 384) {   // weatt for both layers
    int i = threadIdx.x;   // 256 threads
#pragma unroll
    for (int l = 0; l < 2; l++) {
      const float* We = l ? We2 : We1;
      const float* at = l ? atte2 : atte1;
      float* wo = l ? weatt2 : weatt1;
      float p = We[i] * at[i];
#pragma unroll
      for (int off = 1; off < 64; off <<= 1) p += __shfl_xor(p, off, 64);
      if ((i & 63) == 0) wo[i >> 6] = p;
    }
    return;
  }
  const float* W; unsigned short* Wt; int K, t;
  if (b < 128) { W = W1; Wt = Wt1; K = 128; t = b * 256 + threadIdx.x; }
  else         { W = W2; Wt = Wt2; K = 256; t = (b - 128) * 256 + threadIdx.x; }
  int n = t & 255, k = t >> 8;
  if (k >= K) return;
  Wt[(size_t)n * K + k] = f2bf(W[(size_t)k * 256 + n]);
}

// ---------------- MFMA bf16 GEMM + fused attention dots + per-head asrc max ----------------
// BM=128 x BN=256, BK=64, 512 thr = 8 waves, register-prefetch double buffer.
// NEW (r14): gmax via LDS combine -> ONE atomicMax per head per block (was 2).

template <int AF32>
__device__ inline bf16x8 load_a_row(const void* Ain, int gr, int K, int kpos, int M) {
  bf16x8 v = {};
  if (gr < M) {
    if (AF32) {
      const float* src = (const float*)Ain + (size_t)gr * K + kpos;
      float4 f0 = *(const float4*)src;
      float4 f1 = *(const float4*)(src + 4);
      v[0] = (short)f2bf(f0.x); v[1] = (short)f2bf(f0.y);
      v[2] = (short)f2bf(f0.z); v[3] = (short)f2bf(f0.w);
      v[4] = (short)f2bf(f1.x); v[5] = (short)f2bf(f1.y);
      v[6] = (short)f2bf(f1.z); v[7] = (short)f2bf(f1.w);
    } else {
      v = *(const bf16x8*)((const unsigned short*)Ain + (size_t)gr * K + kpos);
    }
  }
  return v;
}

#define CS_STRIDE 264   // shorts per epilogue row (256 + 8 pad)

template <int AF32>
__global__ __launch_bounds__(512) void gemm_att(const void* __restrict__ Ain,
                                                const unsigned short* __restrict__ Wt,
                                                unsigned short* __restrict__ Hb,
                                                const float* __restrict__ atts,
                                                const float* __restrict__ attd,
                                                float* __restrict__ asrc,
                                                float* __restrict__ adst,
                                                unsigned* __restrict__ gmaxk,
                                                int M, int K) {
  __shared__ __align__(16) short smem[(128 + 256) * 64];   // 48 KB
  __shared__ float gmx[8];
  short* As = smem;
  short* Bs = smem + 128 * 64;
  short* Cs = smem;                 // epilogue half-tile [64][CS_STRIDE]
  const int tid = threadIdx.x;
  const int lane = tid & 63, wv = tid >> 6;
  const int wm = wv >> 2, wn = wv & 3;
  const int l15 = lane & 15, l4 = lane >> 4;
  const int bm = blockIdx.x * 128;

  const int r0 = tid >> 3, kc = (tid & 7) * 8;
  const int nbB = tid >> 3, cB = (tid & 7) * 8;

  f32x4 acc[4][4] = {};
  bf16x8 ra0, ra1, rb0, rb1, rb2, rb3;

#define GLOAD_TILE(K0, A0, A1, B0, B1, B2, B3)                                 \
  {                                                                            \
    A0 = load_a_row<AF32>(Ain, bm + r0, K, (K0) + kc, M);                      \
    A1 = load_a_row<AF32>(Ain, bm + r0 + 64, K, (K0) + kc, M);                 \
    B0 = *(const bf16x8*)&Wt[(size_t)(nbB +   0) * K + (K0) + cB];             \
    B1 = *(const bf16x8*)&Wt[(size_t)(nbB +  64) * K + (K0) + cB];             \
    B2 = *(const bf16x8*)&Wt[(size_t)(nbB + 128) * K + (K0) + cB];             \
    B3 = *(const bf16x8*)&Wt[(size_t)(nbB + 192) * K + (K0) + cB];             \
  }

  GLOAD_TILE(0, ra0, ra1, rb0, rb1, rb2, rb3)

  for (int k0 = 0; k0 < K; k0 += 64) {
    *(bf16x8*)&As[((r0) * 64 + kc) ^ ((r0 & 7) << 3)] = ra0;
    *(bf16x8*)&As[((r0 + 64) * 64 + kc) ^ ((r0 & 7) << 3)] = ra1;
    *(bf16x8*)&Bs[((nbB) * 64 + cB) ^ ((nbB & 7) << 3)] = rb0;
    *(bf16x8*)&Bs[((nbB + 64) * 64 + cB) ^ ((nbB & 7) << 3)] = rb1;
    *(bf16x8*)&Bs[((nbB + 128) * 64 + cB) ^ ((nbB & 7) << 3)] = rb2;
    *(bf16x8*)&Bs[((nbB + 192) * 64 + cB) ^ ((nbB & 7) << 3)] = rb3;
    __syncthreads();

    bool more = (k0 + 64 < K);
    bf16x8 na0, na1, nb0, nb1, nb2, nb3;
    if (more) GLOAD_TILE(k0 + 64, na0, na1, nb0, nb1, nb2, nb3)

    bf16x8 af[4][2], bfr[4][2];
#pragma unroll
    for (int rt = 0; rt < 4; rt++)
#pragma unroll
      for (int ks = 0; ks < 2; ks++) {
        int row = wm * 64 + rt * 16 + l15;
        int kb = l4 * 8 + ks * 32;
        af[rt][ks] = *(const bf16x8*)&As[(row * 64 + kb) ^ ((row & 7) << 3)];
      }
#pragma unroll
    for (int ct = 0; ct < 4; ct++)
#pragma unroll
      for (int ks = 0; ks < 2; ks++) {
        int n = wn * 64 + ct * 16 + l15;
        int kb = l4 * 8 + ks * 32;
        bfr[ct][ks] = *(const bf16x8*)&Bs[(n * 64 + kb) ^ ((n & 7) << 3)];
      }
#pragma unroll
    for (int rt = 0; rt < 4; rt++)
#pragma unroll
      for (int ct = 0; ct < 4; ct++)
#pragma unroll
        for (int ks = 0; ks < 2; ks++)
          acc[rt][ct] = __builtin_amdgcn_mfma_f32_16x16x32_bf16(
              af[rt][ks], bfr[ct][ks], acc[rt][ct], 0, 0, 0);
    __syncthreads();

    if (more) { ra0 = na0; ra1 = na1; rb0 = nb0; rb1 = nb1; rb2 = nb2; rb3 = nb3; }
  }
#undef GLOAD_TILE

  // ---- epilogue 1: a_src/a_dst partials (registers only) ----
  float s_att[4], d_att[4];
#pragma unroll
  for (int ct = 0; ct < 4; ct++) {
    s_att[ct] = atts[wn * 64 + ct * 16 + l15];
    d_att[ct] = attd[wn * 64 + ct * 16 + l15];
  }
  float ps[4][4] = {}, pd[4][4] = {};
#pragma unroll
  for (int rt = 0; rt < 4; rt++)
#pragma unroll
    for (int ct = 0; ct < 4; ct++)
#pragma unroll
      for (int i = 0; i < 4; i++) {
        float v = acc[rt][ct][i];
        ps[rt][i] = fmaf(v, s_att[ct], ps[rt][i]);
        pd[rt][i] = fmaf(v, d_att[ct], pd[rt][i]);
      }

  // ---- epilogue 1b: reduce, asrc/adst stores, per-wave max -> LDS ----
#pragma unroll
  for (int rt = 0; rt < 4; rt++)
#pragma unroll
    for (int i = 0; i < 4; i++) {
#pragma unroll
      for (int off = 1; off < 16; off <<= 1) {
        ps[rt][i] += __shfl_xor(ps[rt][i], off, 64);
        pd[rt][i] += __shfl_xor(pd[rt][i], off, 64);
      }
    }
  float mx = ps[0][0];
#pragma unroll
  for (int rt = 0; rt < 4; rt++)
#pragma unroll
    for (int i = 0; i < 4; i++) mx = fmaxf(mx, ps[rt][i]);
  mx = fmaxf(mx, __shfl_xor(mx, 16, 64));
  mx = fmaxf(mx, __shfl_xor(mx, 32, 64));
  if (lane == 0) gmx[wv] = mx;
  if (l15 == 0) {
#pragma unroll
    for (int rt = 0; rt < 4; rt++)
#pragma unroll
      for (int i = 0; i < 4; i++) {
        int gr = bm + wm * 64 + rt * 16 + l4 * 4 + i;
        if (gr < M) {
          asrc[gr * 4 + wn] = ps[rt][i];
          adst[gr * 4 + wn] = pd[rt][i];
        }
      }
  }

  // ---- epilogue 2: Hb store via two 64-row LDS passes (coalesced uint4) ----
  for (int h = 0; h < 2; h++) {
    __syncthreads();
    if (wm == h) {
#pragma unroll
      for (int rt = 0; rt < 4; rt++)
#pragma unroll
        for (int ct = 0; ct < 4; ct++)
#pragma unroll
          for (int i = 0; i < 4; i++) {
            int lrow = rt * 16 + l4 * 4 + i;
            Cs[lrow * CS_STRIDE + wn * 64 + ct * 16 + l15] = f2bf(acc[rt][ct][i]);
          }
    }
    __syncthreads();
    int row = tid >> 3, seg = tid & 7;
    int gr = bm + h * 64 + row;
    if (gr < M) {
      const short* srcr = &Cs[row * CS_STRIDE + seg * 32];
      unsigned short* dstr = &Hb[(size_t)gr * 256 + seg * 32];
#pragma unroll
      for (int k = 0; k < 4; k++)
        *(uint4*)&dstr[k * 8] = *(const uint4*)&srcr[k * 8];
    }
  }

  // ---- epilogue 3: ONE atomicMax per head per block ----
  if (wv < 4 && lane == 0) {
    float m2 = fmaxf(gmx[wv], gmx[wv + 4]);
    atomicMax(&gmaxk[wv * 32], fkey(m2));
  }
}

// ---------------- softmax + aggregation: chunk-16 alpha sharing (unchanged) ----------------

#define AGG_PH1(CNT)                                                        \
  int src = 0; float w = 0.f;                                               \
  if (il < (CNT)) {                                                         \
    int2 e = epack[p + il];                                                 \
    float al = fmaf(__int_as_float(e.y), wa, asrc[e.x * 4 + hh] + ad);      \
    al = fmaxf(al, NEG_SLOPE * al);                                         \
    w = __expf(al - b);                                                     \
    src = e.x;                                                              \
  }                                                                         \
  ssum += w;

#define AGG_GATHER(i)                                                       \
  {                                                                         \
    int sl = (i) | hb16;                                                    \
    int si = __shfl(src, sl, 64);                                           \
    float wi = __shfl(w, sl, 64);                                           \
    uint2 hv = *(const uint2*)&Hb[(size_t)((unsigned)si * 256u + co)];      \
    acc.x = fmaf(wi, __uint_as_float(hv.x << 16), acc.x);                   \
    acc.y = fmaf(wi, __uint_as_float(hv.x & 0xffff0000u), acc.y);           \
    acc.z = fmaf(wi, __uint_as_float(hv.y << 16), acc.z);                   \
    acc.w = fmaf(wi, __uint_as_float(hv.y & 0xffff0000u), acc.w);           \
  }

template <int OUTBF>
__global__ __launch_bounds__(256) void gat_agg(const unsigned short* __restrict__ Hb,
                                               const float* __restrict__ asrc,
                                               const float* __restrict__ adst,
                                               const int* __restrict__ rowptr,
                                               const int2* __restrict__ epack,
                                               const float* __restrict__ weatt,
                                               const unsigned* __restrict__ gmaxk,
                                               const float* __restrict__ bias,
                                               unsigned short* __restrict__ outb,
                                               float* __restrict__ outf, int Nn) {
  int wid = (blockIdx.x * blockDim.x + threadIdx.x) >> 6;
  int lane = threadIdx.x & 63;
  if (wid >= Nn) return;
  int beg = rowptr[wid], end = rowptr[wid + 1];
  int hh = lane >> 4;
  int il = lane & 15;
  int hb16 = lane & 48;
  float wa = weatt[hh];
  float ad = adst[wid * 4 + hh];
  float braw = ad + fkey_dec(gmaxk[hh * 32]) + fmaxf(wa, 0.f);
  float b = fmaxf(braw, NEG_SLOPE * braw);
  unsigned co = (unsigned)lane * 4u;

  float ssum = 0.f;
  float4 acc = {0.f, 0.f, 0.f, 0.f};

  int p = beg;
  for (; p + 16 <= end; p += 16) {
    AGG_PH1(16)
#pragma unroll
    for (int i = 0; i < 16; i++) AGG_GATHER(i)
  }
  int cnt = end - p;
  if (cnt > 0) {
    AGG_PH1(cnt)
    for (int i = 0; i < cnt; i++) AGG_GATHER(i)
  }

#pragma unroll
  for (int off = 1; off < 16; off <<= 1) ssum += __shfl_xor(ssum, off, 64);

  float inv = 1.f / (ssum + 1e-16f);
  float4 b4 = *(const float4*)&bias[co];
  float4 r;
  r.x = fmaf(acc.x, inv, b4.x);
  r.y = fmaf(acc.y, inv, b4.y);
  r.z = fmaf(acc.z, inv, b4.z);
  r.w = fmaf(acc.w, inv, b4.w);
  if (OUTBF) {
    unsigned lo = (unsigned)f2bf(r.x) | ((unsigned)f2bf(r.y) << 16);
    unsigned hi = (unsigned)f2bf(r.z) | ((unsigned)f2bf(r.w) << 16);
    *(uint2*)&outb[(size_t)wid * 256 + co] = make_uint2(lo, hi);
  } else {
    *(float4*)&outf[(size_t)wid * 256 + co] = r;
  }
}

// ---------------- launcher ----------------

extern "C" void kernel_launch(void* const* d_in, const int* in_sizes, int n_in,
                              void* d_out, int out_size, void* d_ws, size_t ws_size,
                              hipStream_t stream) {
  (void)n_in; (void)out_size; (void)ws_size;
  const float* x     = (const float*)d_in[0];
  const int*   ei    = (const int*)d_in[1];
  const float* eattr = (const float*)d_in[3];
  const float* W1    = (const float*)d_in[4];
  const float* We1   = (const float*)d_in[5];
  const float* atts1 = (const float*)d_in[6];
  const float* attd1 = (const float*)d_in[7];
  const float* atte1 = (const float*)d_in[8];
  const float* b1    = (const float*)d_in[9];
  const float* W2    = (const float*)d_in[10];
  const float* We2   = (const float*)d_in[11];
  const float* atts2 = (const float*)d_in[12];
  const float* attd2 = (const float*)d_in[13];
  const float* atte2 = (const float*)d_in[14];
  const float* b2    = (const float*)d_in[15];
  float* out = (float*)d_out;

  const int Nn   = in_sizes[0] / 128;   // 50000
  const int E    = in_sizes[1] / 2;     // 800000
  const int Etot = E + Nn;              // 850000

  char* p = (char*)d_ws;
  auto alloc = [&](size_t bytes) { void* r = (void*)p; p += (bytes + 255) & ~(size_t)255; return r; };
  // zero-init region (single memset): counts + gmax keys (padded)
  int*      counts  = (int*)alloc((size_t)Nn * 4);
  unsigned* gmaxk1  = (unsigned*)alloc(512);   // 4 heads x 128B stride
  unsigned* gmaxk2  = (unsigned*)alloc(512);
  char* zero_end = p;
  int*   rowptr  = (int*)alloc((size_t)(Nn + 1) * 4);
  int*   cursor  = (int*)alloc((size_t)Nn * 4);
  int2*  epack   = (int2*)alloc((size_t)Etot * 8);
  float* meanpart= (float*)alloc(512 * 4);
  float* meanv   = (float*)alloc(4);
  float* weatt1  = (float*)alloc(16);
  float* weatt2  = (float*)alloc(16);
  float* asrc    = (float*)alloc((size_t)Nn * 4 * 4);
  float* adst    = (float*)alloc((size_t)Nn * 4 * 4);
  unsigned short* hbuf = (unsigned short*)alloc((size_t)Nn * 256 * 2);
  unsigned short* h1b  = (unsigned short*)alloc((size_t)Nn * 256 * 2);
  unsigned short* Wt1  = (unsigned short*)alloc((size_t)256 * 128 * 2);
  unsigned short* Wt2  = (unsigned short*)alloc((size_t)256 * 256 * 2);

  hipMemsetAsync(counts, 0, (size_t)(zero_end - (char*)counts), stream);

  hist_kernel<<<(Etot + 255) / 256, 256, 0, stream>>>(ei, counts, E, Etot);
  mean_kernel<<<512, 256, 0, stream>>>(eattr, meanpart, E);
  scan_all<<<1, 1024, 0, stream>>>(counts, rowptr, cursor, meanpart, meanv, Nn, E, 512);
  scatter_kernel<<<(Etot + 255) / 256, 256, 0, stream>>>(ei, eattr, meanv, cursor, epack, E, Etot);
  wtrans_kernel<<<385, 256, 0, stream>>>(W1, Wt1, W2, Wt2, We1, atte1, We2, atte2,
                                         weatt1, weatt2);

  const int gemmBlocks = (Nn + 127) / 128;   // 391
  const int nodeBlocks = (Nn + 3) / 4;

  // ---- layer 1 ----
  gemm_att<1><<<gemmBlocks, 512, 0, stream>>>(x, Wt1, hbuf, atts1, attd1,
                                              asrc, adst, gmaxk1, Nn, 128);
  gat_agg<1><<<nodeBlocks, 256, 0, stream>>>(hbuf, asrc, adst, rowptr, epack,
                                             weatt1, gmaxk1, b1, h1b, nullptr, Nn);
  // ---- layer 2 ----
  gemm_att<0><<<gemmBlocks, 512, 0, stream>>>(h1b, Wt2, hbuf, atts2, attd2,
                                              asrc, adst, gmaxk2, Nn, 256);
  gat_agg<0><<<nodeBlocks, 256, 0, stream>>>(hbuf, asrc, adst, rowptr, epack,
                                             weatt2, gmaxk2, b2, nullptr, out, Nn);
}

// Round 15
// 320.070 us; speedup vs baseline: 1.2765x; 1.2765x over previous
//
#include <hip/hip_runtime.h>

#define NEG_SLOPE 0.2f

typedef __attribute__((ext_vector_type(8))) short bf16x8;
typedef __attribute__((ext_vector_type(4))) float f32x4;

__device__ inline unsigned short f2bf(float x) {
  unsigned int u = __float_as_uint(x);
  u += 0x7fffu + ((u >> 16) & 1u);
  return (unsigned short)(u >> 16);
}

// monotone float<->uint key for atomicMax on signed floats
__device__ inline unsigned fkey(float x) {
  unsigned u = __float_as_uint(x);
  return (u >> 31) ? ~u : (u | 0x80000000u);
}
__device__ inline float fkey_dec(unsigned k) {
  unsigned u = (k & 0x80000000u) ? (k ^ 0x80000000u) : ~k;
  return __uint_as_float(u);
}

// ---------------- CSR build ----------------

__global__ void hist_kernel(const int* __restrict__ ei, int* __restrict__ counts,
                            int E, int Etot) {
  int e = blockIdx.x * blockDim.x + threadIdx.x;
  if (e >= Etot) return;
  int d = (e < E) ? ei[E + e] : (e - E);   // self loop dst = e - E
  atomicAdd(&counts[d], 1);
}

// per-block partial sums, ZERO contended atomics
__global__ void mean_kernel(const float* __restrict__ ea, float* __restrict__ part, int E) {
  int i = blockIdx.x * blockDim.x + threadIdx.x;
  float s = 0.f;
  for (; i < E; i += gridDim.x * blockDim.x) s += ea[i];
#pragma unroll
  for (int off = 1; off < 64; off <<= 1) s += __shfl_xor(s, off, 64);
  __shared__ float ws_[4];
  if ((threadIdx.x & 63) == 0) ws_[threadIdx.x >> 6] = s;
  __syncthreads();
  if (threadIdx.x == 0) part[blockIdx.x] = ws_[0] + ws_[1] + ws_[2] + ws_[3];
}

__global__ void scan_blocksum(const int* __restrict__ counts, int* __restrict__ bsum, int Nn) {
  int base = blockIdx.x * 4096 + threadIdx.x * 16;
  int s = 0;
#pragma unroll
  for (int i = 0; i < 16; i++) { int idx = base + i; if (idx < Nn) s += counts[idx]; }
#pragma unroll
  for (int off = 1; off < 64; off <<= 1) s += __shfl_xor(s, off, 64);
  __shared__ int ws_[4];
  if ((threadIdx.x & 63) == 0) ws_[threadIdx.x >> 6] = s;
  __syncthreads();
  if (threadIdx.x == 0) bsum[blockIdx.x] = ws_[0] + ws_[1] + ws_[2] + ws_[3];
}

// 64 threads: serial bsum exclusive scan (nb~13) + parallel meanpart reduce (512)
__global__ void scan_offsets(int* bsum, int nb, int* rowptrN,
                             const float* __restrict__ meanpart, float* meanv,
                             int E, int npart) {
  int t = threadIdx.x;
  float f = 0.f;
  for (int i = t; i < npart; i += 64) f += meanpart[i];
#pragma unroll
  for (int off = 1; off < 64; off <<= 1) f += __shfl_xor(f, off, 64);
  if (t == 0) {
    *meanv = f / (float)E;
    int acc = 0;
    for (int i = 0; i < nb; i++) { int v = bsum[i]; bsum[i] = acc; acc += v; }
    *rowptrN = acc;
  }
}

// writes rowptr AND cursor
__global__ void scan_final(const int* __restrict__ counts, const int* __restrict__ bsum,
                           int* __restrict__ rowptr, int* __restrict__ cursor, int Nn) {
  int base = blockIdx.x * 4096 + threadIdx.x * 16;
  int v[16]; int s = 0;
#pragma unroll
  for (int i = 0; i < 16; i++) { int idx = base + i; v[i] = (idx < Nn) ? counts[idx] : 0; s += v[i]; }
  int lane = threadIdx.x & 63, wv = threadIdx.x >> 6;
  int incl = s;
#pragma unroll
  for (int off = 1; off < 64; off <<= 1) {
    int y = __shfl_up(incl, off, 64);
    if (lane >= off) incl += y;
  }
  __shared__ int wtot[4];
  if (lane == 63) wtot[wv] = incl;
  __syncthreads();
  int run = bsum[blockIdx.x] + incl - s;
  for (int i = 0; i < wv; i++) run += wtot[i];
  for (int i = 0; i < 16; i++) {
    int idx = base + i;
    if (idx < Nn) { rowptr[idx] = run; cursor[idx] = run; }
    run += v[i];
  }
}

// scatter resolves all indirection: epack[pos] = {src, edge_attr_value}
__global__ void scatter_kernel(const int* __restrict__ ei, const float* __restrict__ eattr,
                               const float* __restrict__ meanv,
                               int* __restrict__ cursor, int2* __restrict__ epack,
                               int E, int Etot) {
  int e = blockIdx.x * blockDim.x + threadIdx.x;
  if (e >= Etot) return;
  int d, s; float ea;
  if (e < E) { d = ei[E + e]; s = ei[e]; ea = eattr[e]; }
  else       { d = e - E;     s = e - E; ea = meanv[0]; }
  int pos = atomicAdd(&cursor[d], 1);
  epack[pos] = make_int2(s, __float_as_int(ea));
}

// W transposes + (block 384) we_att dots, one launch.
__global__ void wtrans_kernel(const float* __restrict__ W1, unsigned short* __restrict__ Wt1,
                              const float* __restrict__ W2, unsigned short* __restrict__ Wt2,
                              const float* __restrict__ We1, const float* __restrict__ atte1,
                              const float* __restrict__ We2, const float* __restrict__ atte2,
                              float* __restrict__ weatt1, float* __restrict__ weatt2) {
  int b = blockIdx.x;
  if (b >= 384) {   // weatt for both layers
    int i = threadIdx.x;   // 256 threads
#pragma unroll
    for (int l = 0; l < 2; l++) {
      const float* We = l ? We2 : We1;
      const float* at = l ? atte2 : atte1;
      float* wo = l ? weatt2 : weatt1;
      float p = We[i] * at[i];
#pragma unroll
      for (int off = 1; off < 64; off <<= 1) p += __shfl_xor(p, off, 64);
      if ((i & 63) == 0) wo[i >> 6] = p;
    }
    return;
  }
  const float* W; unsigned short* Wt; int K, t;
  if (b < 128) { W = W1; Wt = Wt1; K = 128; t = b * 256 + threadIdx.x; }
  else         { W = W2; Wt = Wt2; K = 256; t = (b - 128) * 256 + threadIdx.x; }
  int n = t & 255, k = t >> 8;
  if (k >= K) return;
  Wt[(size_t)n * K + k] = f2bf(W[(size_t)k * 256 + n]);
}

// ---------------- MFMA bf16 GEMM + fused attention dots + per-head asrc max ----------------
// BM=128 x BN=256, BK=64, 512 thr = 8 waves, register-prefetch double buffer,
// gmax via LDS combine -> ONE atomicMax per head per block.

template <int AF32>
__device__ inline bf16x8 load_a_row(const void* Ain, int gr, int K, int kpos, int M) {
  bf16x8 v = {};
  if (gr < M) {
    if (AF32) {
      const float* src = (const float*)Ain + (size_t)gr * K + kpos;
      float4 f0 = *(const float4*)src;
      float4 f1 = *(const float4*)(src + 4);
      v[0] = (short)f2bf(f0.x); v[1] = (short)f2bf(f0.y);
      v[2] = (short)f2bf(f0.z); v[3] = (short)f2bf(f0.w);
      v[4] = (short)f2bf(f1.x); v[5] = (short)f2bf(f1.y);
      v[6] = (short)f2bf(f1.z); v[7] = (short)f2bf(f1.w);
    } else {
      v = *(const bf16x8*)((const unsigned short*)Ain + (size_t)gr * K + kpos);
    }
  }
  return v;
}

#define CS_STRIDE 264   // shorts per epilogue row (256 + 8 pad)

template <int AF32>
__global__ __launch_bounds__(512) void gemm_att(const void* __restrict__ Ain,
                                                const unsigned short* __restrict__ Wt,
                                                unsigned short* __restrict__ Hb,
                                                const float* __restrict__ atts,
                                                const float* __restrict__ attd,
                                                float* __restrict__ asrc,
                                                float* __restrict__ adst,
                                                unsigned* __restrict__ gmaxk,
                                                int M, int K) {
  __shared__ __align__(16) short smem[(128 + 256) * 64];   // 48 KB
  __shared__ float gmx[8];
  short* As = smem;
  short* Bs = smem + 128 * 64;
  short* Cs = smem;                 // epilogue half-tile [64][CS_STRIDE]
  const int tid = threadIdx.x;
  const int lane = tid & 63, wv = tid >> 6;
  const int wm = wv >> 2, wn = wv & 3;
  const int l15 = lane & 15, l4 = lane >> 4;
  const int bm = blockIdx.x * 128;

  const int r0 = tid >> 3, kc = (tid & 7) * 8;
  const int nbB = tid >> 3, cB = (tid & 7) * 8;

  f32x4 acc[4][4] = {};
  bf16x8 ra0, ra1, rb0, rb1, rb2, rb3;

#define GLOAD_TILE(K0, A0, A1, B0, B1, B2, B3)                                 \
  {                                                                            \
    A0 = load_a_row<AF32>(Ain, bm + r0, K, (K0) + kc, M);                      \
    A1 = load_a_row<AF32>(Ain, bm + r0 + 64, K, (K0) + kc, M);                 \
    B0 = *(const bf16x8*)&Wt[(size_t)(nbB +   0) * K + (K0) + cB];             \
    B1 = *(const bf16x8*)&Wt[(size_t)(nbB +  64) * K + (K0) + cB];             \
    B2 = *(const bf16x8*)&Wt[(size_t)(nbB + 128) * K + (K0) + cB];             \
    B3 = *(const bf16x8*)&Wt[(size_t)(nbB + 192) * K + (K0) + cB];             \
  }

  GLOAD_TILE(0, ra0, ra1, rb0, rb1, rb2, rb3)

  for (int k0 = 0; k0 < K; k0 += 64) {
    *(bf16x8*)&As[((r0) * 64 + kc) ^ ((r0 & 7) << 3)] = ra0;
    *(bf16x8*)&As[((r0 + 64) * 64 + kc) ^ ((r0 & 7) << 3)] = ra1;
    *(bf16x8*)&Bs[((nbB) * 64 + cB) ^ ((nbB & 7) << 3)] = rb0;
    *(bf16x8*)&Bs[((nbB + 64) * 64 + cB) ^ ((nbB & 7) << 3)] = rb1;
    *(bf16x8*)&Bs[((nbB + 128) * 64 + cB) ^ ((nbB & 7) << 3)] = rb2;
    *(bf16x8*)&Bs[((nbB + 192) * 64 + cB) ^ ((nbB & 7) << 3)] = rb3;
    __syncthreads();

    bool more = (k0 + 64 < K);
    bf16x8 na0, na1, nb0, nb1, nb2, nb3;
    if (more) GLOAD_TILE(k0 + 64, na0, na1, nb0, nb1, nb2, nb3)

    bf16x8 af[4][2], bfr[4][2];
#pragma unroll
    for (int rt = 0; rt < 4; rt++)
#pragma unroll
      for (int ks = 0; ks < 2; ks++) {
        int row = wm * 64 + rt * 16 + l15;
        int kb = l4 * 8 + ks * 32;
        af[rt][ks] = *(const bf16x8*)&As[(row * 64 + kb) ^ ((row & 7) << 3)];
      }
#pragma unroll
    for (int ct = 0; ct < 4; ct++)
#pragma unroll
      for (int ks = 0; ks < 2; ks++) {
        int n = wn * 64 + ct * 16 + l15;
        int kb = l4 * 8 + ks * 32;
        bfr[ct][ks] = *(const bf16x8*)&Bs[(n * 64 + kb) ^ ((n & 7) << 3)];
      }
#pragma unroll
    for (int rt = 0; rt < 4; rt++)
#pragma unroll
      for (int ct = 0; ct < 4; ct++)
#pragma unroll
        for (int ks = 0; ks < 2; ks++)
          acc[rt][ct] = __builtin_amdgcn_mfma_f32_16x16x32_bf16(
              af[rt][ks], bfr[ct][ks], acc[rt][ct], 0, 0, 0);
    __syncthreads();

    if (more) { ra0 = na0; ra1 = na1; rb0 = nb0; rb1 = nb1; rb2 = nb2; rb3 = nb3; }
  }
#undef GLOAD_TILE

  // ---- epilogue 1: a_src/a_dst partials (registers only) ----
  float s_att[4], d_att[4];
#pragma unroll
  for (int ct = 0; ct < 4; ct++) {
    s_att[ct] = atts[wn * 64 + ct * 16 + l15];
    d_att[ct] = attd[wn * 64 + ct * 16 + l15];
  }
  float ps[4][4] = {}, pd[4][4] = {};
#pragma unroll
  for (int rt = 0; rt < 4; rt++)
#pragma unroll
    for (int ct = 0; ct < 4; ct++)
#pragma unroll
      for (int i = 0; i < 4; i++) {
        float v = acc[rt][ct][i];
        ps[rt][i] = fmaf(v, s_att[ct], ps[rt][i]);
        pd[rt][i] = fmaf(v, d_att[ct], pd[rt][i]);
      }

  // ---- epilogue 1b: reduce, asrc/adst stores, per-wave max -> LDS ----
#pragma unroll
  for (int rt = 0; rt < 4; rt++)
#pragma unroll
    for (int i = 0; i < 4; i++) {
#pragma unroll
      for (int off = 1; off < 16; off <<= 1) {
        ps[rt][i] += __shfl_xor(ps[rt][i], off, 64);
        pd[rt][i] += __shfl_xor(pd[rt][i], off, 64);
      }
    }
  float mx = ps[0][0];
#pragma unroll
  for (int rt = 0; rt < 4; rt++)
#pragma unroll
    for (int i = 0; i < 4; i++) mx = fmaxf(mx, ps[rt][i]);
  mx = fmaxf(mx, __shfl_xor(mx, 16, 64));
  mx = fmaxf(mx, __shfl_xor(mx, 32, 64));
  if (lane == 0) gmx[wv] = mx;
  if (l15 == 0) {
#pragma unroll
    for (int rt = 0; rt < 4; rt++)
#pragma unroll
      for (int i = 0; i < 4; i++) {
        int gr = bm + wm * 64 + rt * 16 + l4 * 4 + i;
        if (gr < M) {
          asrc[gr * 4 + wn] = ps[rt][i];
          adst[gr * 4 + wn] = pd[rt][i];
        }
      }
  }

  // ---- epilogue 2: Hb store via two 64-row LDS passes (coalesced uint4) ----
  for (int h = 0; h < 2; h++) {
    __syncthreads();
    if (wm == h) {
#pragma unroll
      for (int rt = 0; rt < 4; rt++)
#pragma unroll
        for (int ct = 0; ct < 4; ct++)
#pragma unroll
          for (int i = 0; i < 4; i++) {
            int lrow = rt * 16 + l4 * 4 + i;
            Cs[lrow * CS_STRIDE + wn * 64 + ct * 16 + l15] = f2bf(acc[rt][ct][i]);
          }
    }
    __syncthreads();
    int row = tid >> 3, seg = tid & 7;
    int gr = bm + h * 64 + row;
    if (gr < M) {
      const short* srcr = &Cs[row * CS_STRIDE + seg * 32];
      unsigned short* dstr = &Hb[(size_t)gr * 256 + seg * 32];
#pragma unroll
      for (int k = 0; k < 4; k++)
        *(uint4*)&dstr[k * 8] = *(const uint4*)&srcr[k * 8];
    }
  }

  // ---- epilogue 3: ONE atomicMax per head per block ----
  if (wv < 4 && lane == 0) {
    float m2 = fmaxf(gmx[wv], gmx[wv + 4]);
    atomicMax(&gmaxk[wv * 32], fkey(m2));
  }
}

// ---------------- softmax + aggregation: chunk-16 alpha sharing (unchanged) ----------------

#define AGG_PH1(CNT)                                                        \
  int src = 0; float w = 0.f;                                               \
  if (il < (CNT)) {                                                         \
    int2 e = epack[p + il];                                                 \
    float al = fmaf(__int_as_float(e.y), wa, asrc[e.x * 4 + hh] + ad);      \
    al = fmaxf(al, NEG_SLOPE * al);                                         \
    w = __expf(al - b);                                                     \
    src = e.x;                                                              \
  }                                                                         \
  ssum += w;

#define AGG_GATHER(i)                                                       \
  {                                                                         \
    int sl = (i) | hb16;                                                    \
    int si = __shfl(src, sl, 64);                                           \
    float wi = __shfl(w, sl, 64);                                           \
    uint2 hv = *(const uint2*)&Hb[(size_t)((unsigned)si * 256u + co)];      \
    acc.x = fmaf(wi, __uint_as_float(hv.x << 16), acc.x);                   \
    acc.y = fmaf(wi, __uint_as_float(hv.x & 0xffff0000u), acc.y);           \
    acc.z = fmaf(wi, __uint_as_float(hv.y << 16), acc.z);                   \
    acc.w = fmaf(wi, __uint_as_float(hv.y & 0xffff0000u), acc.w);           \
  }

template <int OUTBF>
__global__ __launch_bounds__(256) void gat_agg(const unsigned short* __restrict__ Hb,
                                               const float* __restrict__ asrc,
                                               const float* __restrict__ adst,
                                               const int* __restrict__ rowptr,
                                               const int2* __restrict__ epack,
                                               const float* __restrict__ weatt,
                                               const unsigned* __restrict__ gmaxk,
                                               const float* __restrict__ bias,
                                               unsigned short* __restrict__ outb,
                                               float* __restrict__ outf, int Nn) {
  int wid = (blockIdx.x * blockDim.x + threadIdx.x) >> 6;
  int lane = threadIdx.x & 63;
  if (wid >= Nn) return;
  int beg = rowptr[wid], end = rowptr[wid + 1];
  int hh = lane >> 4;
  int il = lane & 15;
  int hb16 = lane & 48;
  float wa = weatt[hh];
  float ad = adst[wid * 4 + hh];
  float braw = ad + fkey_dec(gmaxk[hh * 32]) + fmaxf(wa, 0.f);
  float b = fmaxf(braw, NEG_SLOPE * braw);
  unsigned co = (unsigned)lane * 4u;

  float ssum = 0.f;
  float4 acc = {0.f, 0.f, 0.f, 0.f};

  int p = beg;
  for (; p + 16 <= end; p += 16) {
    AGG_PH1(16)
#pragma unroll
    for (int i = 0; i < 16; i++) AGG_GATHER(i)
  }
  int cnt = end - p;
  if (cnt > 0) {
    AGG_PH1(cnt)
    for (int i = 0; i < cnt; i++) AGG_GATHER(i)
  }

#pragma unroll
  for (int off = 1; off < 16; off <<= 1) ssum += __shfl_xor(ssum, off, 64);

  float inv = 1.f / (ssum + 1e-16f);
  float4 b4 = *(const float4*)&bias[co];
  float4 r;
  r.x = fmaf(acc.x, inv, b4.x);
  r.y = fmaf(acc.y, inv, b4.y);
  r.z = fmaf(acc.z, inv, b4.z);
  r.w = fmaf(acc.w, inv, b4.w);
  if (OUTBF) {
    unsigned lo = (unsigned)f2bf(r.x) | ((unsigned)f2bf(r.y) << 16);
    unsigned hi = (unsigned)f2bf(r.z) | ((unsigned)f2bf(r.w) << 16);
    *(uint2*)&outb[(size_t)wid * 256 + co] = make_uint2(lo, hi);
  } else {
    *(float4*)&outf[(size_t)wid * 256 + co] = r;
  }
}

// ---------------- launcher ----------------

extern "C" void kernel_launch(void* const* d_in, const int* in_sizes, int n_in,
                              void* d_out, int out_size, void* d_ws, size_t ws_size,
                              hipStream_t stream) {
  (void)n_in; (void)out_size; (void)ws_size;
  const float* x     = (const float*)d_in[0];
  const int*   ei    = (const int*)d_in[1];
  const float* eattr = (const float*)d_in[3];
  const float* W1    = (const float*)d_in[4];
  const float* We1   = (const float*)d_in[5];
  const float* atts1 = (const float*)d_in[6];
  const float* attd1 = (const float*)d_in[7];
  const float* atte1 = (const float*)d_in[8];
  const float* b1    = (const float*)d_in[9];
  const float* W2    = (const float*)d_in[10];
  const float* We2   = (const float*)d_in[11];
  const float* atts2 = (const float*)d_in[12];
  const float* attd2 = (const float*)d_in[13];
  const float* atte2 = (const float*)d_in[14];
  const float* b2    = (const float*)d_in[15];
  float* out = (float*)d_out;

  const int Nn   = in_sizes[0] / 128;   // 50000
  const int E    = in_sizes[1] / 2;     // 800000
  const int Etot = E + Nn;              // 850000

  char* p = (char*)d_ws;
  auto alloc = [&](size_t bytes) { void* r = (void*)p; p += (bytes + 255) & ~(size_t)255; return r; };
  // zero-init region (single memset): counts + gmax keys (padded)
  int*      counts  = (int*)alloc((size_t)Nn * 4);
  unsigned* gmaxk1  = (unsigned*)alloc(512);   // 4 heads x 128B stride
  unsigned* gmaxk2  = (unsigned*)alloc(512);
  char* zero_end = p;
  int*   rowptr  = (int*)alloc((size_t)(Nn + 1) * 4);
  int*   cursor  = (int*)alloc((size_t)Nn * 4);
  int2*  epack   = (int2*)alloc((size_t)Etot * 8);
  int*   bsum    = (int*)alloc(64 * 4);
  float* meanpart= (float*)alloc(512 * 4);
  float* meanv   = (float*)alloc(4);
  float* weatt1  = (float*)alloc(16);
  float* weatt2  = (float*)alloc(16);
  float* asrc    = (float*)alloc((size_t)Nn * 4 * 4);
  float* adst    = (float*)alloc((size_t)Nn * 4 * 4);
  unsigned short* hbuf = (unsigned short*)alloc((size_t)Nn * 256 * 2);
  unsigned short* h1b  = (unsigned short*)alloc((size_t)Nn * 256 * 2);
  unsigned short* Wt1  = (unsigned short*)alloc((size_t)256 * 128 * 2);
  unsigned short* Wt2  = (unsigned short*)alloc((size_t)256 * 256 * 2);

  const int NB = (Nn + 4095) / 4096;

  hipMemsetAsync(counts, 0, (size_t)(zero_end - (char*)counts), stream);

  hist_kernel<<<(Etot + 255) / 256, 256, 0, stream>>>(ei, counts, E, Etot);
  mean_kernel<<<512, 256, 0, stream>>>(eattr, meanpart, E);
  scan_blocksum<<<NB, 256, 0, stream>>>(counts, bsum, Nn);
  scan_offsets<<<1, 64, 0, stream>>>(bsum, NB, rowptr + Nn, meanpart, meanv, E, 512);
  scan_final<<<NB, 256, 0, stream>>>(counts, bsum, rowptr, cursor, Nn);
  scatter_kernel<<<(Etot + 255) / 256, 256, 0, stream>>>(ei, eattr, meanv, cursor, epack, E, Etot);
  wtrans_kernel<<<385, 256, 0, stream>>>(W1, Wt1, W2, Wt2, We1, atte1, We2, atte2,
                                         weatt1, weatt2);

  const int gemmBlocks = (Nn + 127) / 128;   // 391
  const int nodeBlocks = (Nn + 3) / 4;

  // ---- layer 1 ----
  gemm_att<1><<<gemmBlocks, 512, 0, stream>>>(x, Wt1, hbuf, atts1, attd1,
                                              asrc, adst, gmaxk1, Nn, 128);
  gat_agg<1><<<nodeBlocks, 256, 0, stream>>>(hbuf, asrc, adst, rowptr, epack,
                                             weatt1, gmaxk1, b1, h1b, nullptr, Nn);
  // ---- layer 2 ----
  gemm_att<0><<<gemmBlocks, 512, 0, stream>>>(h1b, Wt2, hbuf, atts2, attd2,
                                              asrc, adst, gmaxk2, Nn, 256);
  gat_agg<0><<<nodeBlocks, 256, 0, stream>>>(hbuf, asrc, adst, rowptr, epack,
                                             weatt2, gmaxk2, b2, nullptr, out, Nn);
}